// Round 1
// baseline (637.234 us; speedup 1.0000x reference)
//
#include <hip/hip_runtime.h>
#include <hip/hip_bf16.h>

#define NF     128
#define BATCH  64
#define NNODES 4096
#define MROWS  (BATCH * NNODES)       // 262144
#define NEDGE  (BATCH * (NNODES - 1)) // 262080
#define LN_EPS 1e-5f
#define AP     136                    // padded LDS row stride in bf16 elems (272 B)

typedef short  short8  __attribute__((ext_vector_type(8)));
typedef float  float4v __attribute__((ext_vector_type(4)));

__device__ __forceinline__ unsigned short f2bf(float f) {
    union { float f; unsigned u; } v; v.f = f;
    unsigned r = v.u;
    r = r + 0x7FFF + ((r >> 16) & 1);   // RNE
    return (unsigned short)(r >> 16);
}
__device__ __forceinline__ float bf2f(unsigned short b) {
    union { unsigned u; float f; } v; v.u = ((unsigned)b) << 16;
    return v.f;
}

// MODE 0: A = x (fp32) -> GEMM W + LN + ELU -> hout (bf16)
// MODE 1: A = hin (bf16) -> GEMM W + LN + ELU -> hout (bf16)
// MODE 2: A = max(child, parent) gathered from hin -> GEMM W + LN + ELU
//         -> dot Wr2 + br2 -> rout (fp32 scalar per row)
template <int MODE>
__global__ __launch_bounds__(256)
void mlp_kernel(const float* __restrict__ xin,
                const unsigned short* __restrict__ hin,
                const int* __restrict__ pidx,
                const float* __restrict__ W,
                const float* __restrict__ bias,
                const float* __restrict__ gain,
                const float* __restrict__ beta,
                const float* __restrict__ Wr2,
                const float* __restrict__ br2,
                unsigned short* __restrict__ hout,
                float* __restrict__ rout)
{
    __shared__ unsigned short Atile[64 * AP];

    const int tid  = threadIdx.x;
    const int lane = tid & 63;
    const int wave = tid >> 6;
    const int lnm  = lane & 15;   // col-in-tile / row-in-tile for A
    const int qu   = lane >> 4;   // quad
    const int tileBase = blockIdx.x * 64;

    // ---- B fragments (weights) into registers: b[k][n], n = 16c+lnm, k = s*32+qu*8+j
    short8 bfrag[8][4];
    #pragma unroll
    for (int c = 0; c < 8; ++c) {
        #pragma unroll
        for (int s = 0; s < 4; ++s) {
            union { short8 v; short e[8]; } u;
            #pragma unroll
            for (int j = 0; j < 8; ++j) {
                int k = s * 32 + qu * 8 + j;
                int n = c * 16 + lnm;
                u.e[j] = (short)f2bf(W[k * NF + n]);
            }
            bfrag[c][s] = u.v;
        }
    }
    // per-lane epilogue params for its 8 columns
    float bcol[8], gcol[8], becol[8], w2col[8];
    #pragma unroll
    for (int c = 0; c < 8; ++c) {
        int n = c * 16 + lnm;
        bcol[c]  = bias[n];
        gcol[c]  = gain[n];
        becol[c] = beta[n];
        if (MODE == 2) w2col[c] = Wr2[n];
    }
    float br2v = (MODE == 2) ? br2[0] : 0.0f;

    // ---- stage A tile (64 rows x 128 cols, bf16) into LDS ----
    #pragma unroll
    for (int i = 0; i < 8; ++i) {
        int f   = tid + 256 * i;      // 0..2047
        int row = f >> 5;             // 64 rows
        int g4  = f & 31;             // 32 groups of 4 cols
        unsigned short* dst = &Atile[row * AP + g4 * 4];
        if (MODE == 0) {
            const float4v xv = *(const float4v*)(xin + (size_t)(tileBase + row) * NF + g4 * 4);
            dst[0] = f2bf(xv[0]); dst[1] = f2bf(xv[1]);
            dst[2] = f2bf(xv[2]); dst[3] = f2bf(xv[3]);
        } else if (MODE == 1) {
            *(ushort4*)dst = *(const ushort4*)(hin + (size_t)(tileBase + row) * NF + g4 * 4);
        } else {
            int e    = tileBase + row;        // edge id
            int b    = e / 4095;
            int crow = e + b;                 // child row = b*4096 + (e - b*4095)
            int prow = pidx[e];
            ushort4 cv = *(const ushort4*)(hin + (size_t)crow * NF + g4 * 4);
            ushort4 pv = *(const ushort4*)(hin + (size_t)prow * NF + g4 * 4);
            ushort4 mv;
            mv.x = f2bf(fmaxf(bf2f(cv.x), bf2f(pv.x)));
            mv.y = f2bf(fmaxf(bf2f(cv.y), bf2f(pv.y)));
            mv.z = f2bf(fmaxf(bf2f(cv.z), bf2f(pv.z)));
            mv.w = f2bf(fmaxf(bf2f(cv.w), bf2f(pv.w)));
            *(ushort4*)dst = mv;
        }
    }
    __syncthreads();

    // ---- MFMA: 16 rows per wave, full 128 cols ----
    float4v acc[8];
    #pragma unroll
    for (int c = 0; c < 8; ++c) acc[c] = (float4v){0.f, 0.f, 0.f, 0.f};

    const int arow = wave * 16 + lnm;
    #pragma unroll
    for (int s = 0; s < 4; ++s) {
        short8 afrag = *(const short8*)&Atile[arow * AP + s * 32 + qu * 8];
        #pragma unroll
        for (int c = 0; c < 8; ++c)
            acc[c] = __builtin_amdgcn_mfma_f32_16x16x32_bf16(afrag, bfrag[c][s], acc[c], 0, 0, 0);
    }

    // ---- epilogue: +bias, LayerNorm over 128 cols per row, ELU ----
    // C/D layout: col = 16c + lnm, row (within wave tile) = qu*4 + r
    float v[8][4];
    #pragma unroll
    for (int c = 0; c < 8; ++c)
        #pragma unroll
        for (int r = 0; r < 4; ++r) v[c][r] = acc[c][r] + bcol[c];

    #pragma unroll
    for (int r = 0; r < 4; ++r) {
        float s1 = 0.f, s2 = 0.f;
        #pragma unroll
        for (int c = 0; c < 8; ++c) { s1 += v[c][r]; s2 += v[c][r] * v[c][r]; }
        #pragma unroll
        for (int m = 1; m < 16; m <<= 1) {
            s1 += __shfl_xor(s1, m, 16);
            s2 += __shfl_xor(s2, m, 16);
        }
        float mu  = s1 * (1.0f / 128.0f);
        float var = s2 * (1.0f / 128.0f) - mu * mu;
        float rs  = rsqrtf(var + LN_EPS);
        #pragma unroll
        for (int c = 0; c < 8; ++c) {
            float y = (v[c][r] - mu) * rs * gcol[c] + becol[c];
            v[c][r] = (y > 0.f) ? y : expm1f(y);
        }
    }

    if (MODE < 2) {
        #pragma unroll
        for (int r = 0; r < 4; ++r) {
            int row = tileBase + wave * 16 + qu * 4 + r;
            #pragma unroll
            for (int c = 0; c < 8; ++c)
                hout[(size_t)row * NF + c * 16 + lnm] = f2bf(v[c][r]);
        }
    } else {
        #pragma unroll
        for (int r = 0; r < 4; ++r) {
            float t = 0.f;
            #pragma unroll
            for (int c = 0; c < 8; ++c) t += v[c][r] * w2col[c];
            #pragma unroll
            for (int m = 1; m < 16; m <<= 1) t += __shfl_xor(t, m, 16);
            if (lnm == 0) {
                int row = tileBase + wave * 16 + qu * 4 + r;
                rout[row] = t + br2v;
            }
        }
    }
}

__global__ __launch_bounds__(256)
void lse_kernel(const float* __restrict__ r, float* __restrict__ out)
{
    __shared__ float red[256];
    const int b = blockIdx.x;
    const float* rb = r + (size_t)b * 4095;

    float mx = -1e30f;
    for (int i = threadIdx.x; i < 4095; i += 256) mx = fmaxf(mx, rb[i]);
    red[threadIdx.x] = mx;
    __syncthreads();
    for (int s = 128; s > 0; s >>= 1) {
        if (threadIdx.x < s) red[threadIdx.x] = fmaxf(red[threadIdx.x], red[threadIdx.x + s]);
        __syncthreads();
    }
    mx = red[0];
    __syncthreads();

    float sum = 0.f;
    for (int i = threadIdx.x; i < 4095; i += 256) sum += expf(rb[i] - mx);
    red[threadIdx.x] = sum;
    __syncthreads();
    for (int s = 128; s > 0; s >>= 1) {
        if (threadIdx.x < s) red[threadIdx.x] += red[threadIdx.x + s];
        __syncthreads();
    }
    float lse = mx + logf(red[0]);

    for (int i = threadIdx.x; i < 4095; i += 256)
        out[(size_t)b * 4095 + i] = rb[i] - lse;
}

extern "C" void kernel_launch(void* const* d_in, const int* in_sizes, int n_in,
                              void* d_out, int out_size, void* d_ws, size_t ws_size,
                              hipStream_t stream)
{
    const float* x    = (const float*)d_in[0];
    const int*   pidx = (const int*)d_in[1];
    const float* W1   = (const float*)d_in[2];
    const float* b1   = (const float*)d_in[3];
    const float* g1   = (const float*)d_in[4];
    const float* be1  = (const float*)d_in[5];
    const float* W2   = (const float*)d_in[6];
    const float* b2   = (const float*)d_in[7];
    const float* g2   = (const float*)d_in[8];
    const float* be2  = (const float*)d_in[9];
    const float* Wr1  = (const float*)d_in[10];
    const float* br1  = (const float*)d_in[11];
    const float* gr1  = (const float*)d_in[12];
    const float* ber1 = (const float*)d_in[13];
    const float* Wr2  = (const float*)d_in[14];
    const float* br2  = (const float*)d_in[15];
    float* out = (float*)d_out;

    // workspace layout: h1 (bf16, 64 MiB) | h2 (bf16, 64 MiB) | r (fp32, 1 MiB)
    unsigned short* h1 = (unsigned short*)d_ws;
    unsigned short* h2 = h1 + (size_t)MROWS * NF;
    float* rbuf = (float*)(h2 + (size_t)MROWS * NF);

    mlp_kernel<0><<<MROWS / 64, 256, 0, stream>>>(x, nullptr, nullptr,
        W1, b1, g1, be1, nullptr, nullptr, h1, nullptr);
    mlp_kernel<1><<<MROWS / 64, 256, 0, stream>>>(nullptr, h1, nullptr,
        W2, b2, g2, be2, nullptr, nullptr, h2, nullptr);
    mlp_kernel<2><<<NEDGE / 64, 256, 0, stream>>>(nullptr, h2, pidx,
        Wr1, br1, gr1, ber1, Wr2, br2, nullptr, rbuf);
    lse_kernel<<<BATCH, 256, 0, stream>>>(rbuf, out);
}

// Round 2
// 522.416 us; speedup vs baseline: 1.2198x; 1.2198x over previous
//
#include <hip/hip_runtime.h>
#include <hip/hip_bf16.h>

#define NF     128
#define BATCH  64
#define NNODES 4096
#define MROWS  (BATCH * NNODES)       // 262144
#define NEDGE  (BATCH * (NNODES - 1)) // 262080
#define LN_EPS 1e-5f
#define AP     136                    // padded LDS row stride in bf16 elems (272 B)

typedef short  short8  __attribute__((ext_vector_type(8)));
typedef float  float4v __attribute__((ext_vector_type(4)));

__device__ __forceinline__ unsigned short f2bf(float f) {
    union { float f; unsigned u; } v; v.f = f;
    unsigned r = v.u;
    r = r + 0x7FFF + ((r >> 16) & 1);   // RNE
    return (unsigned short)(r >> 16);
}
__device__ __forceinline__ float bf2f(unsigned short b) {
    union { unsigned u; float f; } v; v.u = ((unsigned)b) << 16;
    return v.f;
}

// MODE 0: A = x (fp32) -> GEMM W + LN + ELU -> hout (bf16)
// MODE 1: A = hin (bf16) -> GEMM W + LN + ELU -> hout (bf16)
// MODE 2: A = max(child, parent) gathered from hin -> GEMM W + LN + ELU
//         -> dot Wr2 + br2 -> rout (fp32 scalar per row)
template <int MODE>
__global__ __launch_bounds__(256, 3)
void mlp_kernel(const float* __restrict__ xin,
                const unsigned short* __restrict__ hin,
                const int* __restrict__ pidx,
                const float* __restrict__ W,
                const float* __restrict__ bias,
                const float* __restrict__ gain,
                const float* __restrict__ beta,
                const float* __restrict__ Wr2,
                const float* __restrict__ br2,
                unsigned short* __restrict__ hout,
                float* __restrict__ rout,
                int ntiles)
{
    __shared__ unsigned short Wt[NF * AP];     // W^T bf16: Wt[n*AP + k], 34816 B
    __shared__ unsigned short Atile[64 * AP];  // 17408 B

    const int tid  = threadIdx.x;
    const int lane = tid & 63;
    const int wave = tid >> 6;
    const int lnm  = lane & 15;   // col-in-tile (B/C) / row-in-tile (A)
    const int qu   = lane >> 4;   // quad

    // ---- one-time: stage W (fp32, k-major) into Wt (bf16, n-major) ----
    #pragma unroll
    for (int i = 0; i < 16; ++i) {
        int flat = tid + 256 * i;          // 0..4095
        int k    = flat >> 5;              // 0..127
        int n0   = (flat & 31) * 4;
        float4v wv = *(const float4v*)(W + k * NF + n0);
        Wt[(n0 + 0) * AP + k] = f2bf(wv[0]);
        Wt[(n0 + 1) * AP + k] = f2bf(wv[1]);
        Wt[(n0 + 2) * AP + k] = f2bf(wv[2]);
        Wt[(n0 + 3) * AP + k] = f2bf(wv[3]);
    }
    __syncthreads();

    // ---- one-time: B fragments from LDS: b[k = s*32+qu*8+j][n = 16c+lnm] ----
    short8 bfrag[8][4];
    #pragma unroll
    for (int c = 0; c < 8; ++c)
        #pragma unroll
        for (int s = 0; s < 4; ++s)
            bfrag[c][s] = *(const short8*)&Wt[(c * 16 + lnm) * AP + s * 32 + qu * 8];

    // per-lane epilogue params for its 8 columns
    float bcol[8], gcol[8], becol[8], w2col[8];
    #pragma unroll
    for (int c = 0; c < 8; ++c) {
        int n = c * 16 + lnm;
        bcol[c]  = bias[n];
        gcol[c]  = gain[n];
        becol[c] = beta[n];
        if (MODE == 2) w2col[c] = Wr2[n];
    }
    float br2v = (MODE == 2) ? br2[0] : 0.0f;

    // ---- persistent tile loop ----
    for (int tile = blockIdx.x; tile < ntiles; tile += gridDim.x) {
        const int tileBase = tile * 64;
        __syncthreads();   // Atile reuse: previous iteration's readers done

        // stage A tile (64 rows x 128 cols, bf16) into Atile
        #pragma unroll
        for (int i = 0; i < 8; ++i) {
            int f   = tid + 256 * i;      // 0..2047
            int row = f >> 5;             // 64 rows
            int g4  = f & 31;             // 32 groups of 4 cols
            unsigned short* dst = &Atile[row * AP + g4 * 4];
            if (MODE == 0) {
                const float4v xv = *(const float4v*)(xin + (size_t)(tileBase + row) * NF + g4 * 4);
                dst[0] = f2bf(xv[0]); dst[1] = f2bf(xv[1]);
                dst[2] = f2bf(xv[2]); dst[3] = f2bf(xv[3]);
            } else if (MODE == 1) {
                *(ushort4*)dst = *(const ushort4*)(hin + (size_t)(tileBase + row) * NF + g4 * 4);
            } else {
                int e    = tileBase + row;        // edge id
                int b    = e / 4095;
                int crow = e + b;                 // child row = b*4096 + (e - b*4095)
                int prow = pidx[e];
                ushort4 cv = *(const ushort4*)(hin + (size_t)crow * NF + g4 * 4);
                ushort4 pv = *(const ushort4*)(hin + (size_t)prow * NF + g4 * 4);
                ushort4 mv;
                mv.x = f2bf(fmaxf(bf2f(cv.x), bf2f(pv.x)));
                mv.y = f2bf(fmaxf(bf2f(cv.y), bf2f(pv.y)));
                mv.z = f2bf(fmaxf(bf2f(cv.z), bf2f(pv.z)));
                mv.w = f2bf(fmaxf(bf2f(cv.w), bf2f(pv.w)));
                *(ushort4*)dst = mv;
            }
        }
        __syncthreads();

        // MFMA: 16 rows per wave, full 128 cols
        float4v acc[8];
        #pragma unroll
        for (int c = 0; c < 8; ++c) acc[c] = (float4v){0.f, 0.f, 0.f, 0.f};

        const int arow = wave * 16 + lnm;
        #pragma unroll
        for (int s = 0; s < 4; ++s) {
            short8 afrag = *(const short8*)&Atile[arow * AP + s * 32 + qu * 8];
            #pragma unroll
            for (int c = 0; c < 8; ++c)
                acc[c] = __builtin_amdgcn_mfma_f32_16x16x32_bf16(afrag, bfrag[c][s], acc[c], 0, 0, 0);
        }

        // epilogue: +bias, LayerNorm over 128 cols per row, ELU
        // C/D layout: col = 16c + lnm, row (within wave tile) = qu*4 + r
        float v[8][4];
        #pragma unroll
        for (int c = 0; c < 8; ++c)
            #pragma unroll
            for (int r = 0; r < 4; ++r) v[c][r] = acc[c][r] + bcol[c];

        #pragma unroll
        for (int r = 0; r < 4; ++r) {
            float s1 = 0.f, s2 = 0.f;
            #pragma unroll
            for (int c = 0; c < 8; ++c) { s1 += v[c][r]; s2 += v[c][r] * v[c][r]; }
            #pragma unroll
            for (int m = 1; m < 16; m <<= 1) {
                s1 += __shfl_xor(s1, m, 16);
                s2 += __shfl_xor(s2, m, 16);
            }
            float mu  = s1 * (1.0f / 128.0f);
            float var = s2 * (1.0f / 128.0f) - mu * mu;
            float rs  = rsqrtf(var + LN_EPS);
            #pragma unroll
            for (int c = 0; c < 8; ++c) {
                float y = (v[c][r] - mu) * rs * gcol[c] + becol[c];
                v[c][r] = (y > 0.f) ? y : (__expf(y) - 1.0f);
            }
        }

        if (MODE < 2) {
            // repack through own-wave rows of Atile (in-wave dependency only),
            // then 16B vector stores
            #pragma unroll
            for (int r = 0; r < 4; ++r)
                #pragma unroll
                for (int c = 0; c < 8; ++c)
                    Atile[(wave * 16 + qu * 4 + r) * AP + c * 16 + lnm] = f2bf(v[c][r]);

            const int row16 = lane >> 4;   // 0..3
            const int chunk = lane & 15;   // 0..15
            #pragma unroll
            for (int p = 0; p < 4; ++p) {
                int rr = row16 + 4 * p;    // 0..15
                short8 pk = *(const short8*)&Atile[(wave * 16 + rr) * AP + chunk * 8];
                *(short8*)(hout + (size_t)(tileBase + wave * 16 + rr) * NF + chunk * 8) = pk;
            }
        } else {
            #pragma unroll
            for (int r = 0; r < 4; ++r) {
                float t = 0.f;
                #pragma unroll
                for (int c = 0; c < 8; ++c) t += v[c][r] * w2col[c];
                #pragma unroll
                for (int m = 1; m < 16; m <<= 1) t += __shfl_xor(t, m, 16);
                if (lnm == 0) {
                    int row = tileBase + wave * 16 + qu * 4 + r;
                    rout[row] = t + br2v;
                }
            }
        }
    }
}

__global__ __launch_bounds__(256)
void lse_kernel(const float* __restrict__ r, float* __restrict__ out)
{
    __shared__ float red[256];
    const int b = blockIdx.x;
    const float* rb = r + (size_t)b * 4095;

    float mx = -1e30f;
    for (int i = threadIdx.x; i < 4095; i += 256) mx = fmaxf(mx, rb[i]);
    red[threadIdx.x] = mx;
    __syncthreads();
    for (int s = 128; s > 0; s >>= 1) {
        if (threadIdx.x < s) red[threadIdx.x] = fmaxf(red[threadIdx.x], red[threadIdx.x + s]);
        __syncthreads();
    }
    mx = red[0];
    __syncthreads();

    float sum = 0.f;
    for (int i = threadIdx.x; i < 4095; i += 256) sum += __expf(rb[i] - mx);
    red[threadIdx.x] = sum;
    __syncthreads();
    for (int s = 128; s > 0; s >>= 1) {
        if (threadIdx.x < s) red[threadIdx.x] += red[threadIdx.x + s];
        __syncthreads();
    }
    float lse = mx + __logf(red[0]);

    for (int i = threadIdx.x; i < 4095; i += 256)
        out[(size_t)b * 4095 + i] = rb[i] - lse;
}

extern "C" void kernel_launch(void* const* d_in, const int* in_sizes, int n_in,
                              void* d_out, int out_size, void* d_ws, size_t ws_size,
                              hipStream_t stream)
{
    const float* x    = (const float*)d_in[0];
    const int*   pidx = (const int*)d_in[1];
    const float* W1   = (const float*)d_in[2];
    const float* b1   = (const float*)d_in[3];
    const float* g1   = (const float*)d_in[4];
    const float* be1  = (const float*)d_in[5];
    const float* W2   = (const float*)d_in[6];
    const float* b2   = (const float*)d_in[7];
    const float* g2   = (const float*)d_in[8];
    const float* be2  = (const float*)d_in[9];
    const float* Wr1  = (const float*)d_in[10];
    const float* br1  = (const float*)d_in[11];
    const float* gr1  = (const float*)d_in[12];
    const float* ber1 = (const float*)d_in[13];
    const float* Wr2  = (const float*)d_in[14];
    const float* br2  = (const float*)d_in[15];
    float* out = (float*)d_out;

    // workspace layout: h1 (bf16, 64 MiB) | h2 (bf16, 64 MiB) | r (fp32, 1 MiB)
    unsigned short* h1 = (unsigned short*)d_ws;
    unsigned short* h2 = h1 + (size_t)MROWS * NF;
    float* rbuf = (float*)(h2 + (size_t)MROWS * NF);

    const int GRID = 1024;
    mlp_kernel<0><<<GRID, 256, 0, stream>>>(x, nullptr, nullptr,
        W1, b1, g1, be1, nullptr, nullptr, h1, nullptr, MROWS / 64);
    mlp_kernel<1><<<GRID, 256, 0, stream>>>(nullptr, h1, nullptr,
        W2, b2, g2, be2, nullptr, nullptr, h2, nullptr, MROWS / 64);
    mlp_kernel<2><<<GRID, 256, 0, stream>>>(nullptr, h2, pidx,
        Wr1, br1, gr1, ber1, Wr2, br2, nullptr, rbuf, NEDGE / 64);
    lse_kernel<<<BATCH, 256, 0, stream>>>(rbuf, out);
}